// Round 7
// baseline (192.908 us; speedup 1.0000x reference)
//
#include <hip/hip_runtime.h>
#include <math.h>

// Capsule routing, fused, fp32.
// x: [256][1152][8] = [256][9216] floats  W: [1152][10][16][8]
// out: v [256][10][16] (40960) then c_out broadcast [256][1152][10] (2949120)
//
// Pipeline per iteration: k_scale (W' = c∘W transposed to [k][n]) -> k_s3
// (register-only GEMM, split-K) -> k_rv (reduce slabs + squash) -> k_a
// (agreement T-GEMM, V streamed from global) -> k_sm (softmax).
//
// ws floats: Wp 1474560 | s_part KB*40960 | b1,b2,c2,c3 (11520 ea) |
//            v1,v2 (40960 ea) | dbp0,dbp1 (46080 ea)

// ---------------------------------------------------------------------------
// k_scale: Wp[(r*8+i)*160 + c*16+o] = cij[r][c] * W[r][c][o][i]
__global__ __launch_bounds__(256) void k_scale(const float* __restrict__ W,
                                               const float* __restrict__ cw, // null -> 1/1152
                                               float* __restrict__ Wp)
{
    __shared__ float raw[2560];
    __shared__ float cl[20];
    const int r0 = blockIdx.x * 2;
    const int tid = threadIdx.x;
    if (tid < 20) cl[tid] = cw ? cw[r0 * 10 + tid] : (1.0f / 1152.0f);
    const float4* __restrict__ W4 = reinterpret_cast<const float4*>(W) + (size_t)r0 * 320;
#pragma unroll
    for (int q = 0; q < 3; ++q) {
        const int idx = q * 256 + tid;
        if (idx < 640) *reinterpret_cast<float4*>(&raw[idx * 4]) = W4[idx];
    }
    __syncthreads();
#pragma unroll
    for (int q = 0; q < 10; ++q) {
        const int idx = q * 256 + tid;          // 0..2559
        const int kl = idx / 160, n = idx % 160;
        const int rl = kl >> 3, i = kl & 7, c = n >> 4, o = n & 15;
        Wp[(size_t)(r0 * 8 + kl) * 160 + n] =
            raw[rl * 1280 + c * 128 + o * 8 + i] * cl[rl * 10 + c];
    }
}

// ---------------------------------------------------------------------------
// k_s3: s_part[kb][b][n] = sum_{k in slab} x[b][k] * Wp[k][n]
// Register-only GEMM: no LDS, no barriers. grid = KB slabs x 16 M-tiles.
// block 256 = tng(32) x tmg(8). TM=2 rows, TN=5 (n = tng*4+j | 128+tng).
template<int KB>
__global__ __launch_bounds__(256, 4) void k_s3(const float* __restrict__ x,
                                               const float* __restrict__ Wp,
                                               float* __restrict__ s_part)
{
    constexpr int KR  = 9216 / KB;
    constexpr int KR4 = KR / 4;
    const int kb = blockIdx.x >> 4;
    const int bt = blockIdx.x & 15;
    const int tid = threadIdx.x;
    const int tng = tid & 31;
    const int tmg = tid >> 5;            // 0..7
    const int row0 = bt * 16 + tmg * 2;  // batch rows row0, row0+1

    const float* __restrict__ wb = Wp + (size_t)kb * KR * 160;
    const float* __restrict__ x0 = x + (size_t)row0 * 9216 + kb * KR;  // float stride 9216!
    const float* __restrict__ x1 = x0 + 9216;

    float acc[2][5];
#pragma unroll
    for (int a = 0; a < 2; ++a)
#pragma unroll
        for (int j = 0; j < 5; ++j) acc[a][j] = 0.f;

#pragma unroll 2
    for (int k4 = 0; k4 < KR4; ++k4) {
        float w[4][5];
#pragma unroll
        for (int u = 0; u < 4; ++u) {
            const int kg = k4 * 4 + u;
            const float4 wv = *reinterpret_cast<const float4*>(&wb[kg * 160 + tng * 4]);
            w[u][0] = wv.x; w[u][1] = wv.y; w[u][2] = wv.z; w[u][3] = wv.w;
            w[u][4] = wb[kg * 160 + 128 + tng];
        }
        const float4 xv0 = *reinterpret_cast<const float4*>(&x0[k4 * 4]);
        const float4 xv1 = *reinterpret_cast<const float4*>(&x1[k4 * 4]);
#pragma unroll
        for (int j = 0; j < 5; ++j) {
            acc[0][j] = fmaf(xv0.x, w[0][j], acc[0][j]);
            acc[0][j] = fmaf(xv0.y, w[1][j], acc[0][j]);
            acc[0][j] = fmaf(xv0.z, w[2][j], acc[0][j]);
            acc[0][j] = fmaf(xv0.w, w[3][j], acc[0][j]);
            acc[1][j] = fmaf(xv1.x, w[0][j], acc[1][j]);
            acc[1][j] = fmaf(xv1.y, w[1][j], acc[1][j]);
            acc[1][j] = fmaf(xv1.z, w[2][j], acc[1][j]);
            acc[1][j] = fmaf(xv1.w, w[3][j], acc[1][j]);
        }
    }

#pragma unroll
    for (int mi = 0; mi < 2; ++mi) {
        float* dst = &s_part[(size_t)(kb * 256 + row0 + mi) * 160];
        *reinterpret_cast<float4*>(&dst[tng * 4]) =
            make_float4(acc[mi][0], acc[mi][1], acc[mi][2], acc[mi][3]);
        dst[128 + tng] = acc[mi][4];
    }
}

// ---------------------------------------------------------------------------
// k_rv: dst[e] = squash( sum_kb s_part[kb][e] ), e = b*160 + c*16 + o.
// grid 160 x 256; squash over 16 consecutive lanes (o-group).
template<int KB>
__global__ __launch_bounds__(256) void k_rv(const float* __restrict__ s_part,
                                            float* __restrict__ dst)
{
    const int e = blockIdx.x * 256 + threadIdx.x;
    float s0 = 0.f, s1 = 0.f, s2 = 0.f, s3 = 0.f;
#pragma unroll
    for (int kbv = 0; kbv < KB; kbv += 4) {
        s0 += s_part[(size_t)(kbv + 0) * 40960 + e];
        s1 += s_part[(size_t)(kbv + 1) * 40960 + e];
        s2 += s_part[(size_t)(kbv + 2) * 40960 + e];
        s3 += s_part[(size_t)(kbv + 3) * 40960 + e];
    }
    const float s = (s0 + s1) + (s2 + s3);
    float sq = s * s;
#pragma unroll
    for (int off = 1; off < 16; off <<= 1) sq += __shfl_xor(sq, off, 16);
    const float scale = (sq / (1.f + sq)) / sqrtf(sq + 1e-9f);
    dst[e] = s * scale;
}

// ---------------------------------------------------------------------------
// k_copy: broadcast cij [11520] -> out[40960 + b*11520], float4, wide grid.
__global__ __launch_bounds__(256) void k_copy(const float* __restrict__ cij,
                                              float* __restrict__ out)
{
    const int i = blockIdx.x * 256 + threadIdx.x;
    const float4 v = reinterpret_cast<const float4*>(cij)[i % 2880];
    reinterpret_cast<float4*>(out + 40960)[i] = v;
}

// ---------------------------------------------------------------------------
// k_a: dbp[ks][r][c] = sum_{b in quarter} sum_o u_hat[b,r,c,o] * v[b,c,o]
// via T[m=(r,i)][n=(c,o)] = sum_b x[b][m] v[b][n], W-contraction in epilogue.
// grid 2304 = mb(576, 2 routes) x ks(4, 64-batch quarters); block 128.
// Register-only inner loop: x broadcast VMEM, v coalesced f4+b32 (L2-hot).
__global__ __launch_bounds__(128) void k_a(const float* __restrict__ x,
                                           const float* __restrict__ v,
                                           const float* __restrict__ W,
                                           float* __restrict__ dbp)
{
    __shared__ float dbl[20];
    const int mb = blockIdx.x >> 2;
    const int ks = blockIdx.x & 3;
    const int m0 = mb * 16;
    const int r0 = m0 >> 3;
    const int b0 = ks * 64;
    const int tid = threadIdx.x;
    const int tng = tid & 31;
    const int tmg = tid >> 5;            // rows m0 + tmg*4 .. +3
    if (tid < 20) dbl[tid] = 0.f;

    const float* __restrict__ xr  = x + (size_t)b0 * 9216 + m0 + tmg * 4;  // float stride 9216!
    const float* __restrict__ vr  = v + (size_t)b0 * 160 + tng * 4;
    const float* __restrict__ vr2 = v + (size_t)b0 * 160 + 128 + tng;

    float acc[4][5];
#pragma unroll
    for (int a = 0; a < 4; ++a)
#pragma unroll
        for (int j = 0; j < 5; ++j) acc[a][j] = 0.f;

#pragma unroll 4
    for (int bb = 0; bb < 64; ++bb) {
        const float4 xv = *reinterpret_cast<const float4*>(&xr[(size_t)bb * 9216]);
        const float4 vv = *reinterpret_cast<const float4*>(&vr[(size_t)bb * 160]);
        const float vt  = vr2[(size_t)bb * 160];
        acc[0][0] = fmaf(xv.x, vv.x, acc[0][0]);
        acc[0][1] = fmaf(xv.x, vv.y, acc[0][1]);
        acc[0][2] = fmaf(xv.x, vv.z, acc[0][2]);
        acc[0][3] = fmaf(xv.x, vv.w, acc[0][3]);
        acc[0][4] = fmaf(xv.x, vt,   acc[0][4]);
        acc[1][0] = fmaf(xv.y, vv.x, acc[1][0]);
        acc[1][1] = fmaf(xv.y, vv.y, acc[1][1]);
        acc[1][2] = fmaf(xv.y, vv.z, acc[1][2]);
        acc[1][3] = fmaf(xv.y, vv.w, acc[1][3]);
        acc[1][4] = fmaf(xv.y, vt,   acc[1][4]);
        acc[2][0] = fmaf(xv.z, vv.x, acc[2][0]);
        acc[2][1] = fmaf(xv.z, vv.y, acc[2][1]);
        acc[2][2] = fmaf(xv.z, vv.z, acc[2][2]);
        acc[2][3] = fmaf(xv.z, vv.w, acc[2][3]);
        acc[2][4] = fmaf(xv.z, vt,   acc[2][4]);
        acc[3][0] = fmaf(xv.w, vv.x, acc[3][0]);
        acc[3][1] = fmaf(xv.w, vv.y, acc[3][1]);
        acc[3][2] = fmaf(xv.w, vv.z, acc[3][2]);
        acc[3][3] = fmaf(xv.w, vv.w, acc[3][3]);
        acc[3][4] = fmaf(xv.w, vt,   acc[3][4]);
    }

    // epilogue: contract T-tile with W.
    // j<4: n = tng*4+j  -> cap cf = tng>>2, o = (tng&3)*4 + j
    // j=4: n = 128+tng  -> cap ct = 8 + (tng>>4), o = tng&15
    const int rl = tmg >> 1;             // local route (fixed per thread)
    const int cf = tng >> 2;
    const int ct = 8 + (tng >> 4);
    const int of = (tng & 3) * 4;
    const int ot = tng & 15;
    float pf = 0.f, pt = 0.f;
#pragma unroll
    for (int mi = 0; mi < 4; ++mi) {
        const int ml = tmg * 4 + mi;
        const int i = ml & 7;
        const int r = r0 + rl;
        const float* wf = &W[(((r * 10 + cf) * 16 + of) * 8) + i];
#pragma unroll
        for (int j = 0; j < 4; ++j) pf = fmaf(wf[j * 8], acc[mi][j], pf);
        pt = fmaf(W[(((r * 10 + ct) * 16 + ot) * 8) + i], acc[mi][4], pt);
    }
    __syncthreads();
    atomicAdd(&dbl[rl * 10 + cf], pf);
    atomicAdd(&dbl[rl * 10 + ct], pt);
    __syncthreads();
    if (tid < 20) dbp[(size_t)ks * 11520 + (r0 + tid / 10) * 10 + (tid % 10)] = dbl[tid];
}

// ---------------------------------------------------------------------------
// k_sm: bnew = bprev + (sum_ks dbp[ks])/256 ; c = softmax over routes per cap
__global__ __launch_bounds__(128) void k_sm(const float* __restrict__ bprev,
                                            const float* __restrict__ dbp,
                                            float* __restrict__ bnew,
                                            float* __restrict__ cij)
{
    __shared__ float red[2];
    __shared__ float red2[2];
    const int c = blockIdx.x;
    const int tid = threadIdx.x;
    float bv[9];
#pragma unroll
    for (int j = 0; j < 9; ++j) {
        const int idx = (tid + j * 128) * 10 + c;
        const float d = dbp[idx] + dbp[11520 + idx] + dbp[23040 + idx] + dbp[34560 + idx];
        bv[j] = (bprev ? bprev[idx] : 0.f) + d * (1.0f / 256.0f);
    }
    float mx = bv[0];
#pragma unroll
    for (int j = 1; j < 9; ++j) mx = fmaxf(mx, bv[j]);
#pragma unroll
    for (int off = 1; off < 64; off <<= 1) mx = fmaxf(mx, __shfl_xor(mx, off, 64));
    if ((tid & 63) == 0) red[tid >> 6] = mx;
    __syncthreads();
    mx = fmaxf(red[0], red[1]);
    float es[9], lsum = 0.f;
#pragma unroll
    for (int j = 0; j < 9; ++j) { es[j] = expf(bv[j] - mx); lsum += es[j]; }
#pragma unroll
    for (int off = 1; off < 64; off <<= 1) lsum += __shfl_xor(lsum, off, 64);
    if ((tid & 63) == 0) red2[tid >> 6] = lsum;
    __syncthreads();
    const float inv = 1.f / (red2[0] + red2[1]);
#pragma unroll
    for (int j = 0; j < 9; ++j) {
        const int idx = (tid + j * 128) * 10 + c;
        bnew[idx] = bv[j];
        cij[idx] = es[j] * inv;
    }
}

// ---------------------------------------------------------------------------
extern "C" void kernel_launch(void* const* d_in, const int* in_sizes, int n_in,
                              void* d_out, int out_size, void* d_ws, size_t ws_size,
                              hipStream_t stream)
{
    const float* x = (const float*)d_in[0];
    const float* W = (const float*)d_in[1];
    float* out = (float*)d_out;
    float* ws  = (float*)d_ws;

    const size_t misc = 4 * 11520 + 2 * 40960 + 2 * 46080;
    const size_t need64 = (1474560UL + 64UL * 40960 + misc) * 4;
    const int KB = (ws_size >= need64) ? 64 : 32;

    float* Wp     = ws;
    float* s_part = ws + 1474560;
    float* b1   = s_part + (size_t)KB * 40960;
    float* b2   = b1 + 11520;
    float* c2   = b2 + 11520;
    float* c3   = c2 + 11520;
    float* v1   = c3 + 11520;
    float* v2   = v1 + 40960;
    float* dbp0 = v2 + 40960;
    float* dbp1 = dbp0 + 46080;

    auto run_s = [&](const float* cwv) {
        k_scale<<<576, 256, 0, stream>>>(W, cwv, Wp);
        if (KB == 64) k_s3<64><<<16 * 64, 256, 0, stream>>>(x, Wp, s_part);
        else          k_s3<32><<<16 * 32, 256, 0, stream>>>(x, Wp, s_part);
    };
    auto run_rv = [&](float* dst) {
        if (KB == 64) k_rv<64><<<160, 256, 0, stream>>>(s_part, dst);
        else          k_rv<32><<<160, 256, 0, stream>>>(s_part, dst);
    };

    // ---- iteration 1 (c uniform = 1/1152) ----
    run_s(nullptr);
    run_rv(v1);
    k_a<<<2304, 128, 0, stream>>>(x, v1, W, dbp0);
    k_sm<<<10, 128, 0, stream>>>(nullptr, dbp0, b1, c2);

    // ---- iteration 2 ----
    run_s(c2);
    run_rv(v2);
    k_a<<<2304, 128, 0, stream>>>(x, v2, W, dbp1);
    k_sm<<<10, 128, 0, stream>>>(b1, dbp1, b2, c3);

    // ---- iteration 3 + outputs ----
    run_s(c3);
    run_rv(out);
    k_copy<<<2880, 256, 0, stream>>>(c3, out);
}

// Round 8
// 164.745 us; speedup vs baseline: 1.1709x; 1.1709x over previous
//
#include <hip/hip_runtime.h>
#include <math.h>

// Capsule routing, fused. GEMM via bf16 hi/lo-split MFMA (hh+hl+lh), rest fp32.
// x: [256][9216] f32   W: [1152][10][16][8] f32
// out: v [256][10][16] (40960) then c_out broadcast [256][1152][10] (2949120)
//
// ws: xh,xl [256][9216] bf16 | wph,wpl [160][9216] bf16 (c∘W, transposed) |
//     s_part [96][256][160] f32 | v1,v2 | b1,b2,c2,c3 | dbp0,dbp1

typedef __attribute__((ext_vector_type(8))) short short8v;
typedef __attribute__((ext_vector_type(4))) float f32x4;

__device__ __forceinline__ unsigned short f2bf(float f) {
    unsigned u = __float_as_uint(f);
    u += 0x7FFFu + ((u >> 16) & 1u);          // round-to-nearest-even
    return (unsigned short)(u >> 16);
}
__device__ __forceinline__ float bf2f(unsigned short h) {
    return __uint_as_float(((unsigned)h) << 16);
}

// ---------------------------------------------------------------------------
// k_xsplit: x -> bf16 hi + bf16 lo residual. Runs once (x is constant).
__global__ __launch_bounds__(256) void k_xsplit(const float* __restrict__ x,
                                                unsigned short* __restrict__ xh,
                                                unsigned short* __restrict__ xl)
{
    const int i = blockIdx.x * 256 + threadIdx.x;   // float4 index, 589824 total
    const float4 v = reinterpret_cast<const float4*>(x)[i];
    const unsigned short h0 = f2bf(v.x), h1 = f2bf(v.y), h2 = f2bf(v.z), h3 = f2bf(v.w);
    const unsigned short l0 = f2bf(v.x - bf2f(h0)), l1 = f2bf(v.y - bf2f(h1)),
                         l2 = f2bf(v.z - bf2f(h2)), l3 = f2bf(v.w - bf2f(h3));
    reinterpret_cast<uint2*>(xh)[i] =
        make_uint2((unsigned)h0 | ((unsigned)h1 << 16), (unsigned)h2 | ((unsigned)h3 << 16));
    reinterpret_cast<uint2*>(xl)[i] =
        make_uint2((unsigned)l0 | ((unsigned)l1 << 16), (unsigned)l2 | ((unsigned)l3 << 16));
}

// ---------------------------------------------------------------------------
// k_scale2: wp{h,l}[n][k] = bf16_split( cij[r][c] * W[r][c][o][i] ),
// n = c*16+o (160), k = r*8+i (9216). grid 576 (2 routes/block), block 256.
__global__ __launch_bounds__(256) void k_scale2(const float* __restrict__ W,
                                                const float* __restrict__ cw, // null -> 1/1152
                                                unsigned short* __restrict__ wph,
                                                unsigned short* __restrict__ wpl)
{
    __shared__ float raw[2560];
    __shared__ float cl[20];
    const int r0 = blockIdx.x * 2;
    const int tid = threadIdx.x;
    if (tid < 20) cl[tid] = cw ? cw[r0 * 10 + tid] : (1.0f / 1152.0f);
    const float4* __restrict__ W4 = reinterpret_cast<const float4*>(W) + (size_t)r0 * 320;
#pragma unroll
    for (int q = 0; q < 3; ++q) {
        const int idx = q * 256 + tid;
        if (idx < 640) *reinterpret_cast<float4*>(&raw[idx * 4]) = W4[idx];
    }
    __syncthreads();
#pragma unroll
    for (int q = 0; q < 10; ++q) {
        const int idx = q * 256 + tid;           // 0..2559
        const int n = idx >> 4, kloc = idx & 15; // k = r0*8 + kloc
        const int rl = kloc >> 3, i = kloc & 7, c = n >> 4, o = n & 15;
        const float wv = raw[rl * 1280 + c * 128 + o * 8 + i] * cl[rl * 10 + c];
        const unsigned short h = f2bf(wv);
        const size_t off = (size_t)n * 9216 + r0 * 8 + kloc;
        wph[off] = h;
        wpl[off] = f2bf(wv - bf2f(h));
    }
}

// ---------------------------------------------------------------------------
// k_sM: s_part[kb][b][n] = sum_{k in slab} x[b][k] * Wp[n][k], bf16x3 MFMA.
// grid 768 = kb(96, KR=96) x mt(4, BM=64) x nt(2, BN=80); block 256 = 4 waves.
// Wave w: rows mt*64+w*16..+15, all 80 n of its half (5 16x16 tiles).
// A-frag: lane holds x[row=l&15][k=(l>>4)*8+j]; B-frag: Wp[n=l&15][same k].
// C/D: col=lane&15, row=(lane>>4)*4+reg (m89-verified).
__global__ __launch_bounds__(256) void k_sM(const unsigned short* __restrict__ xh,
                                            const unsigned short* __restrict__ xl,
                                            const unsigned short* __restrict__ wph,
                                            const unsigned short* __restrict__ wpl,
                                            float* __restrict__ s_part)
{
    const int bid = blockIdx.x;
    const int kb = bid >> 3;
    const int mt = (bid >> 1) & 3;
    const int nt = bid & 1;
    const int w    = threadIdx.x >> 6;
    const int lane = threadIdx.x & 63;
    const int l15  = lane & 15;
    const int lqw  = lane >> 4;
    const int row  = mt * 64 + w * 16 + l15;
    const int k0   = kb * 96 + lqw * 8;
    const int n0   = nt * 80;

    f32x4 acc[5];
#pragma unroll
    for (int t = 0; t < 5; ++t) acc[t] = (f32x4){0.f, 0.f, 0.f, 0.f};

    const size_t arow = (size_t)row * 9216;
#pragma unroll
    for (int ks = 0; ks < 3; ++ks) {
        const size_t ka = arow + k0 + ks * 32;
        const short8v ah = *reinterpret_cast<const short8v*>(xh + ka);
        const short8v al = *reinterpret_cast<const short8v*>(xl + ka);
#pragma unroll
        for (int t = 0; t < 5; ++t) {
            const size_t bo = (size_t)(n0 + t * 16 + l15) * 9216 + k0 + ks * 32;
            const short8v bh = *reinterpret_cast<const short8v*>(wph + bo);
            const short8v bl = *reinterpret_cast<const short8v*>(wpl + bo);
            acc[t] = __builtin_amdgcn_mfma_f32_16x16x32_bf16(ah, bh, acc[t], 0, 0, 0);
            acc[t] = __builtin_amdgcn_mfma_f32_16x16x32_bf16(ah, bl, acc[t], 0, 0, 0);
            acc[t] = __builtin_amdgcn_mfma_f32_16x16x32_bf16(al, bh, acc[t], 0, 0, 0);
        }
    }

    const int crow0 = mt * 64 + w * 16 + lqw * 4;
#pragma unroll
    for (int t = 0; t < 5; ++t) {
#pragma unroll
        for (int v = 0; v < 4; ++v) {
            s_part[((size_t)kb * 256 + crow0 + v) * 160 + n0 + t * 16 + l15] = acc[t][v];
        }
    }
}

// ---------------------------------------------------------------------------
// k_rv: dst[e] = squash( sum_kb s_part[kb][e] ), e = b*160 + c*16 + o.
// grid 160 x 256; squash over 16 consecutive lanes (o-group).
template<int KB>
__global__ __launch_bounds__(256) void k_rv(const float* __restrict__ s_part,
                                            float* __restrict__ dst)
{
    const int e = blockIdx.x * 256 + threadIdx.x;
    float s0 = 0.f, s1 = 0.f, s2 = 0.f, s3 = 0.f;
#pragma unroll
    for (int kbv = 0; kbv < KB; kbv += 4) {
        s0 += s_part[(size_t)(kbv + 0) * 40960 + e];
        s1 += s_part[(size_t)(kbv + 1) * 40960 + e];
        s2 += s_part[(size_t)(kbv + 2) * 40960 + e];
        s3 += s_part[(size_t)(kbv + 3) * 40960 + e];
    }
    const float s = (s0 + s1) + (s2 + s3);
    float sq = s * s;
#pragma unroll
    for (int off = 1; off < 16; off <<= 1) sq += __shfl_xor(sq, off, 16);
    const float scale = (sq / (1.f + sq)) / sqrtf(sq + 1e-9f);
    dst[e] = s * scale;
}

// ---------------------------------------------------------------------------
// k_copy: broadcast cij [11520] -> out[40960 + b*11520], float4, wide grid.
__global__ __launch_bounds__(256) void k_copy(const float* __restrict__ cij,
                                              float* __restrict__ out)
{
    const int i = blockIdx.x * 256 + threadIdx.x;
    const float4 v = reinterpret_cast<const float4*>(cij)[i % 2880];
    reinterpret_cast<float4*>(out + 40960)[i] = v;
}

// ---------------------------------------------------------------------------
// k_a: dbp[ks][r][c] = sum_{b in quarter} sum_o u_hat[b,r,c,o] * v[b,c,o]
// via T[m=(r,i)][n=(c,o)] = sum_b x[b][m] v[b][n], W-contraction in epilogue.
// grid 2304 = mb(576, 2 routes) x ks(4, 64-batch quarters); block 128.
__global__ __launch_bounds__(128) void k_a(const float* __restrict__ x,
                                           const float* __restrict__ v,
                                           const float* __restrict__ W,
                                           float* __restrict__ dbp)
{
    __shared__ float dbl[20];
    const int mb = blockIdx.x >> 2;
    const int ks = blockIdx.x & 3;
    const int m0 = mb * 16;
    const int r0 = m0 >> 3;
    const int b0 = ks * 64;
    const int tid = threadIdx.x;
    const int tng = tid & 31;
    const int tmg = tid >> 5;
    if (tid < 20) dbl[tid] = 0.f;

    const float* __restrict__ xr  = x + (size_t)b0 * 9216 + m0 + tmg * 4;
    const float* __restrict__ vr  = v + (size_t)b0 * 160 + tng * 4;
    const float* __restrict__ vr2 = v + (size_t)b0 * 160 + 128 + tng;

    float acc[4][5];
#pragma unroll
    for (int a = 0; a < 4; ++a)
#pragma unroll
        for (int j = 0; j < 5; ++j) acc[a][j] = 0.f;

#pragma unroll 4
    for (int bb = 0; bb < 64; ++bb) {
        const float4 xv = *reinterpret_cast<const float4*>(&xr[(size_t)bb * 9216]);
        const float4 vv = *reinterpret_cast<const float4*>(&vr[(size_t)bb * 160]);
        const float vt  = vr2[(size_t)bb * 160];
        acc[0][0] = fmaf(xv.x, vv.x, acc[0][0]);
        acc[0][1] = fmaf(xv.x, vv.y, acc[0][1]);
        acc[0][2] = fmaf(xv.x, vv.z, acc[0][2]);
        acc[0][3] = fmaf(xv.x, vv.w, acc[0][3]);
        acc[0][4] = fmaf(xv.x, vt,   acc[0][4]);
        acc[1][0] = fmaf(xv.y, vv.x, acc[1][0]);
        acc[1][1] = fmaf(xv.y, vv.y, acc[1][1]);
        acc[1][2] = fmaf(xv.y, vv.z, acc[1][2]);
        acc[1][3] = fmaf(xv.y, vv.w, acc[1][3]);
        acc[1][4] = fmaf(xv.y, vt,   acc[1][4]);
        acc[2][0] = fmaf(xv.z, vv.x, acc[2][0]);
        acc[2][1] = fmaf(xv.z, vv.y, acc[2][1]);
        acc[2][2] = fmaf(xv.z, vv.z, acc[2][2]);
        acc[2][3] = fmaf(xv.z, vv.w, acc[2][3]);
        acc[2][4] = fmaf(xv.z, vt,   acc[2][4]);
        acc[3][0] = fmaf(xv.w, vv.x, acc[3][0]);
        acc[3][1] = fmaf(xv.w, vv.y, acc[3][1]);
        acc[3][2] = fmaf(xv.w, vv.z, acc[3][2]);
        acc[3][3] = fmaf(xv.w, vv.w, acc[3][3]);
        acc[3][4] = fmaf(xv.w, vt,   acc[3][4]);
    }

    const int rl = tmg >> 1;
    const int cf = tng >> 2;
    const int ct = 8 + (tng >> 4);
    const int of = (tng & 3) * 4;
    const int ot = tng & 15;
    float pf = 0.f, pt = 0.f;
#pragma unroll
    for (int mi = 0; mi < 4; ++mi) {
        const int ml = tmg * 4 + mi;
        const int i = ml & 7;
        const int r = r0 + rl;
        const float* wf = &W[(((r * 10 + cf) * 16 + of) * 8) + i];
#pragma unroll
        for (int j = 0; j < 4; ++j) pf = fmaf(wf[j * 8], acc[mi][j], pf);
        pt = fmaf(W[(((r * 10 + ct) * 16 + ot) * 8) + i], acc[mi][4], pt);
    }
    __syncthreads();
    atomicAdd(&dbl[rl * 10 + cf], pf);
    atomicAdd(&dbl[rl * 10 + ct], pt);
    __syncthreads();
    if (tid < 20) dbp[(size_t)ks * 11520 + (r0 + tid / 10) * 10 + (tid % 10)] = dbl[tid];
}

// ---------------------------------------------------------------------------
// k_sm: bnew = bprev + (sum_ks dbp[ks])/256 ; c = softmax over routes per cap
__global__ __launch_bounds__(128) void k_sm(const float* __restrict__ bprev,
                                            const float* __restrict__ dbp,
                                            float* __restrict__ bnew,
                                            float* __restrict__ cij)
{
    __shared__ float red[2];
    __shared__ float red2[2];
    const int c = blockIdx.x;
    const int tid = threadIdx.x;
    float bv[9];
#pragma unroll
    for (int j = 0; j < 9; ++j) {
        const int idx = (tid + j * 128) * 10 + c;
        const float d = dbp[idx] + dbp[11520 + idx] + dbp[23040 + idx] + dbp[34560 + idx];
        bv[j] = (bprev ? bprev[idx] : 0.f) + d * (1.0f / 256.0f);
    }
    float mx = bv[0];
#pragma unroll
    for (int j = 1; j < 9; ++j) mx = fmaxf(mx, bv[j]);
#pragma unroll
    for (int off = 1; off < 64; off <<= 1) mx = fmaxf(mx, __shfl_xor(mx, off, 64));
    if ((tid & 63) == 0) red[tid >> 6] = mx;
    __syncthreads();
    mx = fmaxf(red[0], red[1]);
    float es[9], lsum = 0.f;
#pragma unroll
    for (int j = 0; j < 9; ++j) { es[j] = expf(bv[j] - mx); lsum += es[j]; }
#pragma unroll
    for (int off = 1; off < 64; off <<= 1) lsum += __shfl_xor(lsum, off, 64);
    if ((tid & 63) == 0) red2[tid >> 6] = lsum;
    __syncthreads();
    const float inv = 1.f / (red2[0] + red2[1]);
#pragma unroll
    for (int j = 0; j < 9; ++j) {
        const int idx = (tid + j * 128) * 10 + c;
        bnew[idx] = bv[j];
        cij[idx] = es[j] * inv;
    }
}

// ---------------------------------------------------------------------------
extern "C" void kernel_launch(void* const* d_in, const int* in_sizes, int n_in,
                              void* d_out, int out_size, void* d_ws, size_t ws_size,
                              hipStream_t stream)
{
    const float* x = (const float*)d_in[0];
    const float* W = (const float*)d_in[1];
    float* out = (float*)d_out;
    float* ws  = (float*)d_ws;

    unsigned short* xh  = (unsigned short*)ws;        // 2359296
    unsigned short* xl  = xh + 2359296;               // 2359296
    unsigned short* wph = xl + 2359296;               // 1474560
    unsigned short* wpl = wph + 1474560;              // 1474560
    float* s_part = ws + 3833856;                     // 96*40960 = 3932160
    float* v1   = s_part + 3932160;
    float* v2   = v1 + 40960;
    float* b1   = v2 + 40960;
    float* b2   = b1 + 11520;
    float* c2   = b2 + 11520;
    float* c3   = c2 + 11520;
    float* dbp0 = c3 + 11520;
    float* dbp1 = dbp0 + 46080;
    // total 7,986,176 floats = 31.9 MB (ws measured 268 MB)

    // x bf16 hi/lo split — once, reused by all 3 iterations
    k_xsplit<<<2304, 256, 0, stream>>>(x, xh, xl);

    // ---- iteration 1 (c uniform = 1/1152) ----
    k_scale2<<<576, 256, 0, stream>>>(W, nullptr, wph, wpl);
    k_sM<<<768, 256, 0, stream>>>(xh, xl, wph, wpl, s_part);
    k_rv<96><<<160, 256, 0, stream>>>(s_part, v1);
    k_a<<<2304, 128, 0, stream>>>(x, v1, W, dbp0);
    k_sm<<<10, 128, 0, stream>>>(nullptr, dbp0, b1, c2);

    // ---- iteration 2 ----
    k_scale2<<<576, 256, 0, stream>>>(W, c2, wph, wpl);
    k_sM<<<768, 256, 0, stream>>>(xh, xl, wph, wpl, s_part);
    k_rv<96><<<160, 256, 0, stream>>>(s_part, v2);
    k_a<<<2304, 128, 0, stream>>>(x, v2, W, dbp1);
    k_sm<<<10, 128, 0, stream>>>(b1, dbp1, b2, c3);

    // ---- iteration 3 + outputs ----
    k_scale2<<<576, 256, 0, stream>>>(W, c3, wph, wpl);
    k_sM<<<768, 256, 0, stream>>>(xh, xl, wph, wpl, s_part);
    k_rv<96><<<160, 256, 0, stream>>>(s_part, out);
    k_copy<<<2880, 256, 0, stream>>>(c3, out);
}

// Round 9
// 141.325 us; speedup vs baseline: 1.3650x; 1.1657x over previous
//
#include <hip/hip_runtime.h>
#include <math.h>

// Capsule routing, fused. GEMM via bf16 hi/lo-split MFMA (hh+hl+lh), rest fp32.
// x: [256][9216] f32   W: [1152][10][16][8] f32
// out: v [256][10][16] (40960) then c_out broadcast [256][1152][10] (2949120)
//
// ws: xh,xl [256][9216] bf16 | wph,wpl [160][9216] bf16 (c∘W, [n][k]) |
//     s_part [96][256][160] f32 | v1,v2 | b1,b2,c2,c3 | dbp0,dbp1

typedef __attribute__((ext_vector_type(8))) short short8v;
typedef __attribute__((ext_vector_type(4))) float f32x4;

__device__ __forceinline__ unsigned short f2bf(float f) {
    unsigned u = __float_as_uint(f);
    u += 0x7FFFu + ((u >> 16) & 1u);          // round-to-nearest-even
    return (unsigned short)(u >> 16);
}
__device__ __forceinline__ float bf2f(unsigned short h) {
    return __uint_as_float(((unsigned)h) << 16);
}

// ---------------------------------------------------------------------------
// k_prep: blocks 0..2303 split x into bf16 hi/lo; blocks 2304..2879 write
// const-scaled (1/1152) W' hi/lo in [n][k] layout (iteration-1 c_ij).
__global__ __launch_bounds__(256) void k_prep(const float* __restrict__ x,
                                              const float* __restrict__ W,
                                              unsigned short* __restrict__ xh,
                                              unsigned short* __restrict__ xl,
                                              unsigned short* __restrict__ wph,
                                              unsigned short* __restrict__ wpl)
{
    const int tid = threadIdx.x;
    if (blockIdx.x < 2304) {
        const int i = blockIdx.x * 256 + tid;   // float4 index, 589824 total
        const float4 v = reinterpret_cast<const float4*>(x)[i];
        const unsigned short h0 = f2bf(v.x), h1 = f2bf(v.y), h2 = f2bf(v.z), h3 = f2bf(v.w);
        const unsigned short l0 = f2bf(v.x - bf2f(h0)), l1 = f2bf(v.y - bf2f(h1)),
                             l2 = f2bf(v.z - bf2f(h2)), l3 = f2bf(v.w - bf2f(h3));
        reinterpret_cast<uint2*>(xh)[i] =
            make_uint2((unsigned)h0 | ((unsigned)h1 << 16), (unsigned)h2 | ((unsigned)h3 << 16));
        reinterpret_cast<uint2*>(xl)[i] =
            make_uint2((unsigned)l0 | ((unsigned)l1 << 16), (unsigned)l2 | ((unsigned)l3 << 16));
    } else {
        __shared__ float raw[2560];
        const int r0 = (blockIdx.x - 2304) * 2;
        const float sc = 1.0f / 1152.0f;
        const float4* __restrict__ W4 = reinterpret_cast<const float4*>(W) + (size_t)r0 * 320;
#pragma unroll
        for (int q = 0; q < 3; ++q) {
            const int idx = q * 256 + tid;
            if (idx < 640) *reinterpret_cast<float4*>(&raw[idx * 4]) = W4[idx];
        }
        __syncthreads();
#pragma unroll
        for (int q = 0; q < 10; ++q) {
            const int idx = q * 256 + tid;           // 0..2559
            const int n = idx >> 4, kloc = idx & 15;
            const int rl = kloc >> 3, i = kloc & 7, c = n >> 4, o = n & 15;
            const float wv = raw[rl * 1280 + c * 128 + o * 8 + i] * sc;
            const unsigned short h = f2bf(wv);
            const size_t off = (size_t)n * 9216 + r0 * 8 + kloc;
            wph[off] = h;
            wpl[off] = f2bf(wv - bf2f(h));
        }
    }
}

// ---------------------------------------------------------------------------
// k_scale2: wp{h,l}[n][k] = bf16_split( cij[r][c] * W[r][c][o][i] )
__global__ __launch_bounds__(256) void k_scale2(const float* __restrict__ W,
                                                const float* __restrict__ cw,
                                                unsigned short* __restrict__ wph,
                                                unsigned short* __restrict__ wpl)
{
    __shared__ float raw[2560];
    __shared__ float cl[20];
    const int r0 = blockIdx.x * 2;
    const int tid = threadIdx.x;
    if (tid < 20) cl[tid] = cw[r0 * 10 + tid];
    const float4* __restrict__ W4 = reinterpret_cast<const float4*>(W) + (size_t)r0 * 320;
#pragma unroll
    for (int q = 0; q < 3; ++q) {
        const int idx = q * 256 + tid;
        if (idx < 640) *reinterpret_cast<float4*>(&raw[idx * 4]) = W4[idx];
    }
    __syncthreads();
#pragma unroll
    for (int q = 0; q < 10; ++q) {
        const int idx = q * 256 + tid;           // 0..2559
        const int n = idx >> 4, kloc = idx & 15;
        const int rl = kloc >> 3, i = kloc & 7, c = n >> 4, o = n & 15;
        const float wv = raw[rl * 1280 + c * 128 + o * 8 + i] * cl[rl * 10 + c];
        const unsigned short h = f2bf(wv);
        const size_t off = (size_t)n * 9216 + r0 * 8 + kloc;
        wph[off] = h;
        wpl[off] = f2bf(wv - bf2f(h));
    }
}

// ---------------------------------------------------------------------------
// k_sM v2: s_part[kb][b][n] = sum_{k in slab} x[b][k] * Wp[n][k], bf16x3 MFMA.
// grid 768 = kb(96, KR=96) x mt(4, BM=64) x nt(2, BN=80); block 256 = 4 waves.
// B-slab staged ONCE in LDS ([h/l][ch][n][8] chunks: ds-reads hit the even
// 8-words/bank b128 floor); A prefetched to regs before the barrier.
__global__ __launch_bounds__(256) void k_sM(const unsigned short* __restrict__ xh,
                                            const unsigned short* __restrict__ xl,
                                            const unsigned short* __restrict__ wph,
                                            const unsigned short* __restrict__ wpl,
                                            float* __restrict__ s_part)
{
    __shared__ alignas(16) short Bs[2][12][80][8];   // 30720 B
    const int bid = blockIdx.x;
    const int kb = bid >> 3;
    const int mt = (bid >> 1) & 3;
    const int nt = bid & 1;
    const int tid  = threadIdx.x;
    const int w    = tid >> 6;
    const int lane = tid & 63;
    const int l15  = lane & 15;
    const int lqw  = lane >> 4;
    const int row  = mt * 64 + w * 16 + l15;
    const int n0   = nt * 80;

    // A prefetch (6 global loads, latency hidden under B staging + barrier)
    short8v ah[3], al[3];
    const size_t arow = (size_t)row * 9216 + kb * 96 + lqw * 8;
#pragma unroll
    for (int ks = 0; ks < 3; ++ks) {
        ah[ks] = *reinterpret_cast<const short8v*>(xh + arow + ks * 32);
        al[ks] = *reinterpret_cast<const short8v*>(xl + arow + ks * 32);
    }

    // B staging: 960 (n,ch) chunks of 16B, global reads row-contiguous
    for (int idx = tid; idx < 960; idx += 256) {
        const int n = idx / 12, ch = idx % 12;
        const size_t g = (size_t)(n0 + n) * 9216 + kb * 96 + ch * 8;
        *reinterpret_cast<short8v*>(&Bs[0][ch][n][0]) =
            *reinterpret_cast<const short8v*>(wph + g);
        *reinterpret_cast<short8v*>(&Bs[1][ch][n][0]) =
            *reinterpret_cast<const short8v*>(wpl + g);
    }
    __syncthreads();

    f32x4 acc[5];
#pragma unroll
    for (int t = 0; t < 5; ++t) acc[t] = (f32x4){0.f, 0.f, 0.f, 0.f};

#pragma unroll
    for (int ks = 0; ks < 3; ++ks) {
        const int ch = ks * 4 + lqw;
#pragma unroll
        for (int t = 0; t < 5; ++t) {
            const short8v bh = *reinterpret_cast<const short8v*>(&Bs[0][ch][t * 16 + l15][0]);
            const short8v bl = *reinterpret_cast<const short8v*>(&Bs[1][ch][t * 16 + l15][0]);
            acc[t] = __builtin_amdgcn_mfma_f32_16x16x32_bf16(ah[ks], bh, acc[t], 0, 0, 0);
            acc[t] = __builtin_amdgcn_mfma_f32_16x16x32_bf16(ah[ks], bl, acc[t], 0, 0, 0);
            acc[t] = __builtin_amdgcn_mfma_f32_16x16x32_bf16(al[ks], bh, acc[t], 0, 0, 0);
        }
    }

    const int crow0 = mt * 64 + w * 16 + lqw * 4;
#pragma unroll
    for (int t = 0; t < 5; ++t) {
#pragma unroll
        for (int v = 0; v < 4; ++v) {
            s_part[((size_t)kb * 256 + crow0 + v) * 160 + n0 + t * 16 + l15] = acc[t][v];
        }
    }
}

// ---------------------------------------------------------------------------
// k_rv: dst[e] = squash( sum_kb s_part[kb][e] ), e = b*160 + c*16 + o.
template<int KB>
__global__ __launch_bounds__(256) void k_rv(const float* __restrict__ s_part,
                                            float* __restrict__ dst)
{
    const int e = blockIdx.x * 256 + threadIdx.x;
    float s0 = 0.f, s1 = 0.f, s2 = 0.f, s3 = 0.f;
#pragma unroll
    for (int kbv = 0; kbv < KB; kbv += 4) {
        s0 += s_part[(size_t)(kbv + 0) * 40960 + e];
        s1 += s_part[(size_t)(kbv + 1) * 40960 + e];
        s2 += s_part[(size_t)(kbv + 2) * 40960 + e];
        s3 += s_part[(size_t)(kbv + 3) * 40960 + e];
    }
    const float s = (s0 + s1) + (s2 + s3);
    float sq = s * s;
#pragma unroll
    for (int off = 1; off < 16; off <<= 1) sq += __shfl_xor(sq, off, 16);
    const float scale = (sq / (1.f + sq)) / sqrtf(sq + 1e-9f);
    dst[e] = s * scale;
}

// ---------------------------------------------------------------------------
// k_rvc: blocks 0..159 = k_rv into out[0..40960); blocks 160.. copy c3
// broadcast into out[40960 + b*11520] (float4).
__global__ __launch_bounds__(256) void k_rvc(const float* __restrict__ s_part,
                                             const float* __restrict__ cij,
                                             float* __restrict__ out)
{
    const int tid = threadIdx.x;
    if (blockIdx.x < 160) {
        const int e = blockIdx.x * 256 + tid;
        float s0 = 0.f, s1 = 0.f, s2 = 0.f, s3 = 0.f;
#pragma unroll
        for (int kbv = 0; kbv < 96; kbv += 4) {
            s0 += s_part[(size_t)(kbv + 0) * 40960 + e];
            s1 += s_part[(size_t)(kbv + 1) * 40960 + e];
            s2 += s_part[(size_t)(kbv + 2) * 40960 + e];
            s3 += s_part[(size_t)(kbv + 3) * 40960 + e];
        }
        const float s = (s0 + s1) + (s2 + s3);
        float sq = s * s;
#pragma unroll
        for (int off = 1; off < 16; off <<= 1) sq += __shfl_xor(sq, off, 16);
        const float scale = (sq / (1.f + sq)) / sqrtf(sq + 1e-9f);
        out[e] = s * scale;
    } else {
        const int i = (blockIdx.x - 160) * 256 + tid;   // 0..737279 float4
        const float4 v = reinterpret_cast<const float4*>(cij)[i % 2880];
        reinterpret_cast<float4*>(out + 40960)[i] = v;
    }
}

// ---------------------------------------------------------------------------
// k_a: dbp[ks][r][c] = sum_{b in quarter} sum_o u_hat[b,r,c,o] * v[b,c,o]
// grid 2304 = mb(576, 2 routes) x ks(4, 64-batch quarters); block 128.
__global__ __launch_bounds__(128) void k_a(const float* __restrict__ x,
                                           const float* __restrict__ v,
                                           const float* __restrict__ W,
                                           float* __restrict__ dbp)
{
    __shared__ float dbl[20];
    const int mb = blockIdx.x >> 2;
    const int ks = blockIdx.x & 3;
    const int m0 = mb * 16;
    const int r0 = m0 >> 3;
    const int b0 = ks * 64;
    const int tid = threadIdx.x;
    const int tng = tid & 31;
    const int tmg = tid >> 5;
    if (tid < 20) dbl[tid] = 0.f;

    const float* __restrict__ xr  = x + (size_t)b0 * 9216 + m0 + tmg * 4;
    const float* __restrict__ vr  = v + (size_t)b0 * 160 + tng * 4;
    const float* __restrict__ vr2 = v + (size_t)b0 * 160 + 128 + tng;

    float acc[4][5];
#pragma unroll
    for (int a = 0; a < 4; ++a)
#pragma unroll
        for (int j = 0; j < 5; ++j) acc[a][j] = 0.f;

#pragma unroll 4
    for (int bb = 0; bb < 64; ++bb) {
        const float4 xv = *reinterpret_cast<const float4*>(&xr[(size_t)bb * 9216]);
        const float4 vv = *reinterpret_cast<const float4*>(&vr[(size_t)bb * 160]);
        const float vt  = vr2[(size_t)bb * 160];
        acc[0][0] = fmaf(xv.x, vv.x, acc[0][0]);
        acc[0][1] = fmaf(xv.x, vv.y, acc[0][1]);
        acc[0][2] = fmaf(xv.x, vv.z, acc[0][2]);
        acc[0][3] = fmaf(xv.x, vv.w, acc[0][3]);
        acc[0][4] = fmaf(xv.x, vt,   acc[0][4]);
        acc[1][0] = fmaf(xv.y, vv.x, acc[1][0]);
        acc[1][1] = fmaf(xv.y, vv.y, acc[1][1]);
        acc[1][2] = fmaf(xv.y, vv.z, acc[1][2]);
        acc[1][3] = fmaf(xv.y, vv.w, acc[1][3]);
        acc[1][4] = fmaf(xv.y, vt,   acc[1][4]);
        acc[2][0] = fmaf(xv.z, vv.x, acc[2][0]);
        acc[2][1] = fmaf(xv.z, vv.y, acc[2][1]);
        acc[2][2] = fmaf(xv.z, vv.z, acc[2][2]);
        acc[2][3] = fmaf(xv.z, vv.w, acc[2][3]);
        acc[2][4] = fmaf(xv.z, vt,   acc[2][4]);
        acc[3][0] = fmaf(xv.w, vv.x, acc[3][0]);
        acc[3][1] = fmaf(xv.w, vv.y, acc[3][1]);
        acc[3][2] = fmaf(xv.w, vv.z, acc[3][2]);
        acc[3][3] = fmaf(xv.w, vv.w, acc[3][3]);
        acc[3][4] = fmaf(xv.w, vt,   acc[3][4]);
    }

    const int rl = tmg >> 1;
    const int cf = tng >> 2;
    const int ct = 8 + (tng >> 4);
    const int of = (tng & 3) * 4;
    const int ot = tng & 15;
    float pf = 0.f, pt = 0.f;
#pragma unroll
    for (int mi = 0; mi < 4; ++mi) {
        const int ml = tmg * 4 + mi;
        const int i = ml & 7;
        const int r = r0 + rl;
        const float* wf = &W[(((r * 10 + cf) * 16 + of) * 8) + i];
#pragma unroll
        for (int j = 0; j < 4; ++j) pf = fmaf(wf[j * 8], acc[mi][j], pf);
        pt = fmaf(W[(((r * 10 + ct) * 16 + ot) * 8) + i], acc[mi][4], pt);
    }
    __syncthreads();
    atomicAdd(&dbl[rl * 10 + cf], pf);
    atomicAdd(&dbl[rl * 10 + ct], pt);
    __syncthreads();
    if (tid < 20) dbp[(size_t)ks * 11520 + (r0 + tid / 10) * 10 + (tid % 10)] = dbl[tid];
}

// ---------------------------------------------------------------------------
// k_sm: bnew = bprev + (sum_ks dbp[ks])/256 ; c = softmax over routes per cap
__global__ __launch_bounds__(128) void k_sm(const float* __restrict__ bprev,
                                            const float* __restrict__ dbp,
                                            float* __restrict__ bnew,
                                            float* __restrict__ cij)
{
    __shared__ float red[2];
    __shared__ float red2[2];
    const int c = blockIdx.x;
    const int tid = threadIdx.x;
    float bv[9];
#pragma unroll
    for (int j = 0; j < 9; ++j) {
        const int idx = (tid + j * 128) * 10 + c;
        const float d = dbp[idx] + dbp[11520 + idx] + dbp[23040 + idx] + dbp[34560 + idx];
        bv[j] = (bprev ? bprev[idx] : 0.f) + d * (1.0f / 256.0f);
    }
    float mx = bv[0];
#pragma unroll
    for (int j = 1; j < 9; ++j) mx = fmaxf(mx, bv[j]);
#pragma unroll
    for (int off = 1; off < 64; off <<= 1) mx = fmaxf(mx, __shfl_xor(mx, off, 64));
    if ((tid & 63) == 0) red[tid >> 6] = mx;
    __syncthreads();
    mx = fmaxf(red[0], red[1]);
    float es[9], lsum = 0.f;
#pragma unroll
    for (int j = 0; j < 9; ++j) { es[j] = expf(bv[j] - mx); lsum += es[j]; }
#pragma unroll
    for (int off = 1; off < 64; off <<= 1) lsum += __shfl_xor(lsum, off, 64);
    if ((tid & 63) == 0) red2[tid >> 6] = lsum;
    __syncthreads();
    const float inv = 1.f / (red2[0] + red2[1]);
#pragma unroll
    for (int j = 0; j < 9; ++j) {
        const int idx = (tid + j * 128) * 10 + c;
        bnew[idx] = bv[j];
        cij[idx] = es[j] * inv;
    }
}

// ---------------------------------------------------------------------------
extern "C" void kernel_launch(void* const* d_in, const int* in_sizes, int n_in,
                              void* d_out, int out_size, void* d_ws, size_t ws_size,
                              hipStream_t stream)
{
    const float* x = (const float*)d_in[0];
    const float* W = (const float*)d_in[1];
    float* out = (float*)d_out;
    float* ws  = (float*)d_ws;

    unsigned short* xh  = (unsigned short*)ws;        // 2359296
    unsigned short* xl  = xh + 2359296;               // 2359296
    unsigned short* wph = xl + 2359296;               // 1474560
    unsigned short* wpl = wph + 1474560;              // 1474560
    float* s_part = ws + 3833856;                     // 96*40960 = 3932160
    float* v1   = s_part + 3932160;
    float* v2   = v1 + 40960;
    float* b1   = v2 + 40960;
    float* b2   = b1 + 11520;
    float* c2   = b2 + 11520;
    float* c3   = c2 + 11520;
    float* dbp0 = c3 + 11520;
    float* dbp1 = dbp0 + 46080;

    // prep: x hi/lo split + iteration-1 const-scaled W'
    k_prep<<<2880, 256, 0, stream>>>(x, W, xh, xl, wph, wpl);

    // ---- iteration 1 ----
    k_sM<<<768, 256, 0, stream>>>(xh, xl, wph, wpl, s_part);
    k_rv<96><<<160, 256, 0, stream>>>(s_part, v1);
    k_a<<<2304, 128, 0, stream>>>(x, v1, W, dbp0);
    k_sm<<<10, 128, 0, stream>>>(nullptr, dbp0, b1, c2);

    // ---- iteration 2 ----
    k_scale2<<<576, 256, 0, stream>>>(W, c2, wph, wpl);
    k_sM<<<768, 256, 0, stream>>>(xh, xl, wph, wpl, s_part);
    k_rv<96><<<160, 256, 0, stream>>>(s_part, v2);
    k_a<<<2304, 128, 0, stream>>>(x, v2, W, dbp1);
    k_sm<<<10, 128, 0, stream>>>(b1, dbp1, b2, c3);

    // ---- iteration 3 + outputs ----
    k_scale2<<<576, 256, 0, stream>>>(W, c3, wph, wpl);
    k_sM<<<768, 256, 0, stream>>>(xh, xl, wph, wpl, s_part);
    k_rvc<<<3040, 256, 0, stream>>>(s_part, c3, out);
}

// Round 10
// 125.810 us; speedup vs baseline: 1.5333x; 1.1233x over previous
//
#include <hip/hip_runtime.h>
#include <math.h>

// Capsule routing, fused. Both GEMMs via bf16 hi/lo-split MFMA (hh+hl+lh).
// x: [256][9216] f32   W: [1152][10][16][8] f32
// out: v [256][10][16] (40960) then c_out broadcast [256][1152][10] (2949120)

typedef __attribute__((ext_vector_type(8))) short short8v;
typedef __attribute__((ext_vector_type(4))) float f32x4;

__device__ __forceinline__ unsigned short f2bf(float f) {
    unsigned u = __float_as_uint(f);
    u += 0x7FFFu + ((u >> 16) & 1u);          // round-to-nearest-even
    return (unsigned short)(u >> 16);
}
__device__ __forceinline__ float bf2f(unsigned short h) {
    return __uint_as_float(((unsigned)h) << 16);
}

// ---------------------------------------------------------------------------
// k_prep: bid<2304: x -> bf16 hi/lo (row-major [b][k]).
//         2304..2879: const-scaled (1/1152) W' hi/lo in [n][k].
//         2880..3455: xT hi/lo [m=9216][b=256] via LDS transpose.
__global__ __launch_bounds__(256) void k_prep(const float* __restrict__ x,
                                              const float* __restrict__ W,
                                              unsigned short* __restrict__ xh,
                                              unsigned short* __restrict__ xl,
                                              unsigned short* __restrict__ wph,
                                              unsigned short* __restrict__ wpl,
                                              unsigned short* __restrict__ xTh,
                                              unsigned short* __restrict__ xTl)
{
    const int tid = threadIdx.x;
    if (blockIdx.x < 2304) {
        const int i = blockIdx.x * 256 + tid;   // float4 index, 589824 total
        const float4 v = reinterpret_cast<const float4*>(x)[i];
        const unsigned short h0 = f2bf(v.x), h1 = f2bf(v.y), h2 = f2bf(v.z), h3 = f2bf(v.w);
        const unsigned short l0 = f2bf(v.x - bf2f(h0)), l1 = f2bf(v.y - bf2f(h1)),
                             l2 = f2bf(v.z - bf2f(h2)), l3 = f2bf(v.w - bf2f(h3));
        reinterpret_cast<uint2*>(xh)[i] =
            make_uint2((unsigned)h0 | ((unsigned)h1 << 16), (unsigned)h2 | ((unsigned)h3 << 16));
        reinterpret_cast<uint2*>(xl)[i] =
            make_uint2((unsigned)l0 | ((unsigned)l1 << 16), (unsigned)l2 | ((unsigned)l3 << 16));
    } else if (blockIdx.x < 2880) {
        __shared__ float raw[2560];
        const int r0 = (blockIdx.x - 2304) * 2;
        const float sc = 1.0f / 1152.0f;
        const float4* __restrict__ W4 = reinterpret_cast<const float4*>(W) + (size_t)r0 * 320;
#pragma unroll
        for (int q = 0; q < 3; ++q) {
            const int idx = q * 256 + tid;
            if (idx < 640) *reinterpret_cast<float4*>(&raw[idx * 4]) = W4[idx];
        }
        __syncthreads();
#pragma unroll
        for (int q = 0; q < 10; ++q) {
            const int idx = q * 256 + tid;           // 0..2559
            const int n = idx >> 4, kloc = idx & 15;
            const int rl = kloc >> 3, i = kloc & 7, c = n >> 4, o = n & 15;
            const float wv = raw[rl * 1280 + c * 128 + o * 8 + i] * sc;
            const unsigned short h = f2bf(wv);
            const size_t off = (size_t)n * 9216 + r0 * 8 + kloc;
            wph[off] = h;
            wpl[off] = f2bf(wv - bf2f(h));
        }
    } else {
        // xT transpose+split: m-chunk of 16, all 256 b.
        __shared__ short Th[16][256];
        __shared__ short Tl[16][256];
        const int m0 = (blockIdx.x - 2880) * 16;
        const int b = tid;
#pragma unroll
        for (int q = 0; q < 4; ++q) {
            const float4 v = reinterpret_cast<const float4*>(x)[(size_t)b * 2304 + (m0 >> 2) + q];
            const unsigned short h0 = f2bf(v.x), h1 = f2bf(v.y), h2 = f2bf(v.z), h3 = f2bf(v.w);
            Th[q * 4 + 0][b] = (short)h0;
            Th[q * 4 + 1][b] = (short)h1;
            Th[q * 4 + 2][b] = (short)h2;
            Th[q * 4 + 3][b] = (short)h3;
            Tl[q * 4 + 0][b] = (short)f2bf(v.x - bf2f(h0));
            Tl[q * 4 + 1][b] = (short)f2bf(v.y - bf2f(h1));
            Tl[q * 4 + 2][b] = (short)f2bf(v.z - bf2f(h2));
            Tl[q * 4 + 3][b] = (short)f2bf(v.w - bf2f(h3));
        }
        __syncthreads();
        const int m = tid >> 4, seg = tid & 15;
        const size_t o = (size_t)(m0 + m) * 256 + seg * 16;
        *reinterpret_cast<uint4*>(xTh + o) = *reinterpret_cast<const uint4*>(&Th[m][seg * 16]);
        *reinterpret_cast<uint4*>(xTh + o + 8) = *reinterpret_cast<const uint4*>(&Th[m][seg * 16 + 8]);
        *reinterpret_cast<uint4*>(xTl + o) = *reinterpret_cast<const uint4*>(&Tl[m][seg * 16]);
        *reinterpret_cast<uint4*>(xTl + o + 8) = *reinterpret_cast<const uint4*>(&Tl[m][seg * 16 + 8]);
    }
}

// ---------------------------------------------------------------------------
// k_scale2: wp{h,l}[n][k] = bf16_split( cij[r][c] * W[r][c][o][i] )
__global__ __launch_bounds__(256) void k_scale2(const float* __restrict__ W,
                                                const float* __restrict__ cw,
                                                unsigned short* __restrict__ wph,
                                                unsigned short* __restrict__ wpl)
{
    __shared__ float raw[2560];
    __shared__ float cl[20];
    const int r0 = blockIdx.x * 2;
    const int tid = threadIdx.x;
    if (tid < 20) cl[tid] = cw[r0 * 10 + tid];
    const float4* __restrict__ W4 = reinterpret_cast<const float4*>(W) + (size_t)r0 * 320;
#pragma unroll
    for (int q = 0; q < 3; ++q) {
        const int idx = q * 256 + tid;
        if (idx < 640) *reinterpret_cast<float4*>(&raw[idx * 4]) = W4[idx];
    }
    __syncthreads();
#pragma unroll
    for (int q = 0; q < 10; ++q) {
        const int idx = q * 256 + tid;           // 0..2559
        const int n = idx >> 4, kloc = idx & 15;
        const int rl = kloc >> 3, i = kloc & 7, c = n >> 4, o = n & 15;
        const float wv = raw[rl * 1280 + c * 128 + o * 8 + i] * cl[rl * 10 + c];
        const unsigned short h = f2bf(wv);
        const size_t off = (size_t)n * 9216 + r0 * 8 + kloc;
        wph[off] = h;
        wpl[off] = f2bf(wv - bf2f(h));
    }
}

// ---------------------------------------------------------------------------
// k_sM: s_part[kb][b][n] = sum_{k in slab} x[b][k] * Wp[n][k], bf16x3 MFMA.
// grid 768 = kb(96, KR=96) x mt(4, BM=64) x nt(2, BN=80); block 256 = 4 waves.
__global__ __launch_bounds__(256) void k_sM(const unsigned short* __restrict__ xh,
                                            const unsigned short* __restrict__ xl,
                                            const unsigned short* __restrict__ wph,
                                            const unsigned short* __restrict__ wpl,
                                            float* __restrict__ s_part)
{
    __shared__ alignas(16) short Bs[2][12][80][8];   // 30720 B
    const int bid = blockIdx.x;
    const int kb = bid >> 3;
    const int mt = (bid >> 1) & 3;
    const int nt = bid & 1;
    const int tid  = threadIdx.x;
    const int w    = tid >> 6;
    const int lane = tid & 63;
    const int l15  = lane & 15;
    const int lqw  = lane >> 4;
    const int row  = mt * 64 + w * 16 + l15;
    const int n0   = nt * 80;

    short8v ah[3], al[3];
    const size_t arow = (size_t)row * 9216 + kb * 96 + lqw * 8;
#pragma unroll
    for (int ks = 0; ks < 3; ++ks) {
        ah[ks] = *reinterpret_cast<const short8v*>(xh + arow + ks * 32);
        al[ks] = *reinterpret_cast<const short8v*>(xl + arow + ks * 32);
    }

    for (int idx = tid; idx < 960; idx += 256) {
        const int n = idx / 12, ch = idx % 12;
        const size_t g = (size_t)(n0 + n) * 9216 + kb * 96 + ch * 8;
        *reinterpret_cast<short8v*>(&Bs[0][ch][n][0]) =
            *reinterpret_cast<const short8v*>(wph + g);
        *reinterpret_cast<short8v*>(&Bs[1][ch][n][0]) =
            *reinterpret_cast<const short8v*>(wpl + g);
    }
    __syncthreads();

    f32x4 acc[5];
#pragma unroll
    for (int t = 0; t < 5; ++t) acc[t] = (f32x4){0.f, 0.f, 0.f, 0.f};

#pragma unroll
    for (int ks = 0; ks < 3; ++ks) {
        const int ch = ks * 4 + lqw;
#pragma unroll
        for (int t = 0; t < 5; ++t) {
            const short8v bh = *reinterpret_cast<const short8v*>(&Bs[0][ch][t * 16 + l15][0]);
            const short8v bl = *reinterpret_cast<const short8v*>(&Bs[1][ch][t * 16 + l15][0]);
            acc[t] = __builtin_amdgcn_mfma_f32_16x16x32_bf16(ah[ks], bh, acc[t], 0, 0, 0);
            acc[t] = __builtin_amdgcn_mfma_f32_16x16x32_bf16(ah[ks], bl, acc[t], 0, 0, 0);
            acc[t] = __builtin_amdgcn_mfma_f32_16x16x32_bf16(al[ks], bh, acc[t], 0, 0, 0);
        }
    }

    const int crow0 = mt * 64 + w * 16 + lqw * 4;
#pragma unroll
    for (int t = 0; t < 5; ++t) {
#pragma unroll
        for (int v = 0; v < 4; ++v) {
            s_part[((size_t)kb * 256 + crow0 + v) * 160 + n0 + t * 16 + l15] = acc[t][v];
        }
    }
}

// ---------------------------------------------------------------------------
// k_rvT: v[b][n] = squash(sum_kb s_part) -> write bf16 hi/lo TRANSPOSED vT[n][b].
// grid 256 (one b per block), block 192 (160 active = n).
__global__ __launch_bounds__(192) void k_rvT(const float* __restrict__ s_part,
                                             unsigned short* __restrict__ vTh,
                                             unsigned short* __restrict__ vTl)
{
    const int b = blockIdx.x;
    const int n = threadIdx.x;
    if (n < 160) {
        const float* p = s_part + (size_t)b * 160 + n;
        float s0 = 0.f, s1 = 0.f, s2 = 0.f, s3 = 0.f, s4 = 0.f, s5 = 0.f, s6 = 0.f, s7 = 0.f;
#pragma unroll
        for (int kbv = 0; kbv < 96; kbv += 8) {
            s0 += p[(size_t)(kbv + 0) * 40960];
            s1 += p[(size_t)(kbv + 1) * 40960];
            s2 += p[(size_t)(kbv + 2) * 40960];
            s3 += p[(size_t)(kbv + 3) * 40960];
            s4 += p[(size_t)(kbv + 4) * 40960];
            s5 += p[(size_t)(kbv + 5) * 40960];
            s6 += p[(size_t)(kbv + 6) * 40960];
            s7 += p[(size_t)(kbv + 7) * 40960];
        }
        const float s = ((s0 + s1) + (s2 + s3)) + ((s4 + s5) + (s6 + s7));
        float sq = s * s;
#pragma unroll
        for (int off = 1; off < 16; off <<= 1) sq += __shfl_xor(sq, off, 16);
        const float scale = (sq / (1.f + sq)) / sqrtf(sq + 1e-9f);
        const float val = s * scale;
        const unsigned short h = f2bf(val);
        vTh[n * 256 + b] = h;
        vTl[n * 256 + b] = f2bf(val - bf2f(h));
    }
}

// ---------------------------------------------------------------------------
// k_aM: agreement via MFMA. T^T = vT(160x256) x x(256x9216); then
// dbp[kh][r][c] = sum_{i,o} W[r][c][o][i] * T[m=r*8+i][n=c*16+o].
// grid 1152 = mt(576, 16 m = 2 routes) x kh(2, 128-batch halves);
// block 128 = 2 waves (w = n-half of 80). A-frag vT[n][b], B-frag xT[m][b].
__global__ __launch_bounds__(128) void k_aM(const unsigned short* __restrict__ vTh,
                                            const unsigned short* __restrict__ vTl,
                                            const unsigned short* __restrict__ xTh,
                                            const unsigned short* __restrict__ xTl,
                                            const float* __restrict__ W,
                                            float* __restrict__ dbp)
{
    __shared__ float dbl[20];
    const int mt = blockIdx.x >> 1;
    const int kh = blockIdx.x & 1;
    const int m0 = mt * 16;
    const int r0 = m0 >> 3;
    const int b0 = kh * 128;
    const int tid  = threadIdx.x;
    const int w    = tid >> 6;
    const int lane = tid & 63;
    const int l15  = lane & 15;
    const int lqw  = lane >> 4;
    if (tid < 20) dbl[tid] = 0.f;

    const size_t xbase = (size_t)(m0 + l15) * 256 + b0 + lqw * 8;

    f32x4 acc[5];
#pragma unroll
    for (int t = 0; t < 5; ++t) acc[t] = (f32x4){0.f, 0.f, 0.f, 0.f};

#pragma unroll
    for (int ks = 0; ks < 4; ++ks) {
        const short8v bh = *reinterpret_cast<const short8v*>(xTh + xbase + ks * 32);
        const short8v bl = *reinterpret_cast<const short8v*>(xTl + xbase + ks * 32);
#pragma unroll
        for (int t = 0; t < 5; ++t) {
            const size_t vbase = (size_t)(w * 80 + t * 16 + l15) * 256 + b0 + lqw * 8 + ks * 32;
            const short8v ah = *reinterpret_cast<const short8v*>(vTh + vbase);
            const short8v al = *reinterpret_cast<const short8v*>(vTl + vbase);
            acc[t] = __builtin_amdgcn_mfma_f32_16x16x32_bf16(ah, bh, acc[t], 0, 0, 0);
            acc[t] = __builtin_amdgcn_mfma_f32_16x16x32_bf16(ah, bl, acc[t], 0, 0, 0);
            acc[t] = __builtin_amdgcn_mfma_f32_16x16x32_bf16(al, bh, acc[t], 0, 0, 0);
        }
    }

    // epilogue: D[row=n=w*80+t*16+lqw*4+vi][col=m=m0+l15] = T[m][n].
    // r = r0+(l15>>3), i = l15&7, c = w*5+t, o = lqw*4+vi.
    __syncthreads();   // dbl init visible
    const int rloc = l15 >> 3;
    const int i = l15 & 7;
    const int r = r0 + rloc;
#pragma unroll
    for (int t = 0; t < 5; ++t) {
        const int c = w * 5 + t;
        const float* wp = &W[(((size_t)(r * 10 + c) * 16 + lqw * 4) * 8) + i];
        float pv = wp[0] * acc[t][0] + wp[8] * acc[t][1] + wp[16] * acc[t][2] + wp[24] * acc[t][3];
        pv += __shfl_xor(pv, 16);
        pv += __shfl_xor(pv, 32);
        pv += __shfl_xor(pv, 1);
        pv += __shfl_xor(pv, 2);
        pv += __shfl_xor(pv, 4);
        if ((lane & 55) == 0)            // lanes 0 (r0) and 8 (r0+1)
            dbl[rloc * 10 + c] = pv;
    }
    __syncthreads();
    if (tid < 20) dbp[(size_t)kh * 11520 + (r0 + tid / 10) * 10 + (tid % 10)] = dbl[tid];
}

// ---------------------------------------------------------------------------
// k_sm: bnew = bprev + (sum of 2 dbp parts)/256 ; c = softmax over routes
__global__ __launch_bounds__(128) void k_sm(const float* __restrict__ bprev,
                                            const float* __restrict__ dbp,
                                            float* __restrict__ bnew,
                                            float* __restrict__ cij)
{
    __shared__ float red[2];
    __shared__ float red2[2];
    const int c = blockIdx.x;
    const int tid = threadIdx.x;
    float bv[9];
#pragma unroll
    for (int j = 0; j < 9; ++j) {
        const int idx = (tid + j * 128) * 10 + c;
        const float d = dbp[idx] + dbp[11520 + idx];
        bv[j] = (bprev ? bprev[idx] : 0.f) + d * (1.0f / 256.0f);
    }
    float mx = bv[0];
#pragma unroll
    for (int j = 1; j < 9; ++j) mx = fmaxf(mx, bv[j]);
#pragma unroll
    for (int off = 1; off < 64; off <<= 1) mx = fmaxf(mx, __shfl_xor(mx, off, 64));
    if ((tid & 63) == 0) red[tid >> 6] = mx;
    __syncthreads();
    mx = fmaxf(red[0], red[1]);
    float es[9], lsum = 0.f;
#pragma unroll
    for (int j = 0; j < 9; ++j) { es[j] = expf(bv[j] - mx); lsum += es[j]; }
#pragma unroll
    for (int off = 1; off < 64; off <<= 1) lsum += __shfl_xor(lsum, off, 64);
    if ((tid & 63) == 0) red2[tid >> 6] = lsum;
    __syncthreads();
    const float inv = 1.f / (red2[0] + red2[1]);
#pragma unroll
    for (int j = 0; j < 9; ++j) {
        const int idx = (tid + j * 128) * 10 + c;
        bnew[idx] = bv[j];
        cij[idx] = es[j] * inv;
    }
}

// ---------------------------------------------------------------------------
// k_rvc: blocks 0..159 reduce+squash s_part -> out v; blocks 160.. broadcast c3.
__global__ __launch_bounds__(256) void k_rvc(const float* __restrict__ s_part,
                                             const float* __restrict__ cij,
                                             float* __restrict__ out)
{
    const int tid = threadIdx.x;
    if (blockIdx.x < 160) {
        const int e = blockIdx.x * 256 + tid;
        float s0 = 0.f, s1 = 0.f, s2 = 0.f, s3 = 0.f;
#pragma unroll
        for (int kbv = 0; kbv < 96; kbv += 4) {
            s0 += s_part[(size_t)(kbv + 0) * 40960 + e];
            s1 += s_part[(size_t)(kbv + 1) * 40960 + e];
            s2 += s_part[(size_t)(kbv + 2) * 40960 + e];
            s3 += s_part[(size_t)(kbv + 3) * 40960 + e];
        }
        const float s = (s0 + s1) + (s2 + s3);
        float sq = s * s;
#pragma unroll
        for (int off = 1; off < 16; off <<= 1) sq += __shfl_xor(sq, off, 16);
        const float scale = (sq / (1.f + sq)) / sqrtf(sq + 1e-9f);
        out[e] = s * scale;
    } else {
        const int i = (blockIdx.x - 160) * 256 + tid;   // 0..737279 float4
        const float4 v = reinterpret_cast<const float4*>(cij)[i % 2880];
        reinterpret_cast<float4*>(out + 40960)[i] = v;
    }
}

// ---------------------------------------------------------------------------
extern "C" void kernel_launch(void* const* d_in, const int* in_sizes, int n_in,
                              void* d_out, int out_size, void* d_ws, size_t ws_size,
                              hipStream_t stream)
{
    const float* x = (const float*)d_in[0];
    const float* W = (const float*)d_in[1];
    float* out = (float*)d_out;

    unsigned short* xh  = (unsigned short*)d_ws;      // 2359296 shorts each
    unsigned short* xl  = xh + 2359296;
    unsigned short* xTh = xl + 2359296;
    unsigned short* xTl = xTh + 2359296;
    unsigned short* wph = xTl + 2359296;              // 1474560 shorts each
    unsigned short* wpl = wph + 1474560;
    unsigned short* vTh = wpl + 1474560;              // 40960 shorts each
    unsigned short* vTl = vTh + 40960;
    float* s_part = (float*)(vTl + 40960 + 32);       // 96*40960 f32 (aligned pad)
    float* b1   = s_part + 3932160;
    float* b2   = b1 + 11520;
    float* c2   = b2 + 11520;
    float* c3   = c2 + 11520;
    float* dbp0 = c3 + 11520;
    float* dbp1 = dbp0 + 23040;

    // prep: x hi/lo split (row-major + transposed) + iteration-1 const W'
    k_prep<<<3456, 256, 0, stream>>>(x, W, xh, xl, wph, wpl, xTh, xTl);

    // ---- iteration 1 ----
    k_sM<<<768, 256, 0, stream>>>(xh, xl, wph, wpl, s_part);
    k_rvT<<<256, 192, 0, stream>>>(s_part, vTh, vTl);
    k_aM<<<1152, 128, 0, stream>>>(vTh, vTl, xTh, xTl, W, dbp0);
    k_sm<<<10, 128, 0, stream>>>(nullptr, dbp0, b1, c2);

    // ---- iteration 2 ----
    k_scale2<<<576, 256, 0, stream>>>(W, c2, wph, wpl);
    k_sM<<<768, 256, 0, stream>>>(xh, xl, wph, wpl, s_part);
    k_rvT<<<256, 192, 0, stream>>>(s_part, vTh, vTl);
    k_aM<<<1152, 128, 0, stream>>>(vTh, vTl, xTh, xTl, W, dbp1);
    k_sm<<<10, 128, 0, stream>>>(b1, dbp1, b2, c3);

    // ---- iteration 3 + outputs ----
    k_scale2<<<576, 256, 0, stream>>>(W, c3, wph, wpl);
    k_sM<<<768, 256, 0, stream>>>(xh, xl, wph, wpl, s_part);
    k_rvc<<<3040, 256, 0, stream>>>(s_part, c3, out);
}